// Round 1
// baseline (1166.148 us; speedup 1.0000x reference)
//
#include <hip/hip_runtime.h>

#define SLOPE 0.2f

// ---------------- init output with bias ----------------
__global__ void init_out(float* __restrict__ out, const float* __restrict__ bias, int total) {
    int i = blockIdx.x * blockDim.x + threadIdx.x;
    if (i < total) out[i] = bias[i & 127];
}

// ---------------- GEMM: Wh = H @ W  (N x 128 @ 128 x 128, fp32) ----------------
// Block: 256 threads, tile 64 rows x 128 cols. H tile transposed in LDS.
__global__ __launch_bounds__(256) void gemm_wh(const float* __restrict__ H,
                                               const float* __restrict__ W,
                                               float* __restrict__ Wh, int N) {
    __shared__ float HT[128][66];  // [k][r], pad 66 keeps float2 reads 8B-aligned, light conflicts
    const int brow = blockIdx.x * 64;
    const int t = threadIdx.x;

    for (int i = t; i < 64 * 128; i += 256) {
        int r = i >> 7, k = i & 127;
        int gr = brow + r;
        HT[k][r] = (gr < N) ? H[(size_t)gr * 128 + k] : 0.f;
    }
    __syncthreads();

    const int tc = (t & 31) * 4;   // 4 consecutive cols
    const int tr = (t >> 5) * 8;   // 8 consecutive rows
    float acc[8][4];
#pragma unroll
    for (int i = 0; i < 8; ++i)
#pragma unroll
        for (int j = 0; j < 4; ++j) acc[i][j] = 0.f;

    for (int k = 0; k < 128; ++k) {
        float4 w = *reinterpret_cast<const float4*>(&W[k * 128 + tc]);
        float h[8];
#pragma unroll
        for (int i = 0; i < 8; i += 2) {
            float2 h2 = *reinterpret_cast<const float2*>(&HT[k][tr + i]);
            h[i] = h2.x; h[i + 1] = h2.y;
        }
#pragma unroll
        for (int i = 0; i < 8; ++i) {
            acc[i][0] = fmaf(h[i], w.x, acc[i][0]);
            acc[i][1] = fmaf(h[i], w.y, acc[i][1]);
            acc[i][2] = fmaf(h[i], w.z, acc[i][2]);
            acc[i][3] = fmaf(h[i], w.w, acc[i][3]);
        }
    }

#pragma unroll
    for (int i = 0; i < 8; ++i) {
        int gr = brow + tr + i;
        if (gr < N)
            *reinterpret_cast<float4*>(&Wh[(size_t)gr * 128 + tc]) =
                make_float4(acc[i][0], acc[i][1], acc[i][2], acc[i][3]);
    }
}

// ---------------- per-node scores: s_dst = Wh . a[:128], s_src = Wh . a[128:] ----------------
__global__ __launch_bounds__(256) void scores(const float* __restrict__ Wh,
                                              const float* __restrict__ a,
                                              float* __restrict__ s_dst,
                                              float* __restrict__ s_src, int N) {
    int wid = (int)((blockIdx.x * 256 + threadIdx.x) >> 6);
    int lane = threadIdx.x & 63;
    if (wid >= N) return;
    float2 v = *reinterpret_cast<const float2*>(&Wh[(size_t)wid * 128 + lane * 2]);
    float2 ad = *reinterpret_cast<const float2*>(&a[lane * 2]);
    float2 as = *reinterpret_cast<const float2*>(&a[128 + lane * 2]);
    float pd = v.x * ad.x + v.y * ad.y;
    float ps = v.x * as.x + v.y * as.y;
#pragma unroll
    for (int off = 32; off; off >>= 1) {
        pd += __shfl_xor(pd, off);
        ps += __shfl_xor(ps, off);
    }
    if (lane == 0) { s_dst[wid] = pd; s_src[wid] = ps; }
}

// ---------------- histogram of destination rows ----------------
__global__ void hist(const int* __restrict__ row, int* __restrict__ cnt, int E) {
    int i = blockIdx.x * blockDim.x + threadIdx.x;
    if (i < E) atomicAdd(&cnt[row[i]], 1);
}

// ---------------- 3-kernel exclusive scan (in-place over cnt -> offs) ----------------
__global__ __launch_bounds__(256) void scan1(int* __restrict__ data, int* __restrict__ bsum, int N) {
    __shared__ int s[256];
    int i = blockIdx.x * 256 + threadIdx.x;
    int v = (i < N) ? data[i] : 0;
    s[threadIdx.x] = v;
    __syncthreads();
    for (int off = 1; off < 256; off <<= 1) {
        int y = (threadIdx.x >= off) ? s[threadIdx.x - off] : 0;
        __syncthreads();
        s[threadIdx.x] += y;
        __syncthreads();
    }
    if (i < N) data[i] = s[threadIdx.x] - v;  // exclusive
    if (threadIdx.x == 255) bsum[blockIdx.x] = s[255];
}

__global__ __launch_bounds__(512) void scan2(int* __restrict__ bsum, int nb) {
    __shared__ int s[512];
    int t = threadIdx.x;
    int v = (t < nb) ? bsum[t] : 0;
    s[t] = v;
    __syncthreads();
    for (int off = 1; off < 512; off <<= 1) {
        int y = (t >= off) ? s[t - off] : 0;
        __syncthreads();
        s[t] += y;
        __syncthreads();
    }
    if (t < nb) bsum[t] = s[t] - v;  // exclusive over block sums
}

__global__ void scan3(int* __restrict__ offs, const int* __restrict__ bsum, int N, int E) {
    int i = blockIdx.x * blockDim.x + threadIdx.x;
    if (i < N) offs[i] += bsum[i >> 8];
    if (i == 0) offs[N] = E;
}

// ---------------- scatter edge ids into CSR buckets ----------------
__global__ void scatter(const int* __restrict__ row, int* __restrict__ cursor,
                        int* __restrict__ eidx, int E) {
    int i = blockIdx.x * blockDim.x + threadIdx.x;
    if (i < E) {
        int pos = atomicAdd(&cursor[row[i]], 1);
        eidx[pos] = i;
    }
}

// ---------------- aggregation: one wave per destination node ----------------
__global__ __launch_bounds__(256) void aggregate(const float* __restrict__ Wh,
                                                 const float* __restrict__ s_dst,
                                                 const float* __restrict__ s_src,
                                                 const int* __restrict__ col,
                                                 const int* __restrict__ offs,
                                                 const int* __restrict__ eidx,
                                                 float* __restrict__ out, int N) {
    int wid = (int)((blockIdx.x * 256 + threadIdx.x) >> 6);
    int lane = threadIdx.x & 63;
    if (wid >= N) return;
    int beg = offs[wid], end = offs[wid + 1];
    if (beg == end) return;
    float sd = s_dst[wid];

    // pass 1: max over edges (lanes split edges)
    float m = -1e30f;
    for (int j = beg + lane; j < end; j += 64) {
        int e = eidx[j];
        int c = col[e];
        float x = sd + s_src[c];
        x = (x > 0.f) ? x : SLOPE * x;
        m = fmaxf(m, x);
    }
#pragma unroll
    for (int off = 32; off; off >>= 1) m = fmaxf(m, __shfl_xor(m, off));

    // pass 2: all lanes cooperate per edge; lane owns 2 output columns
    float wsum = 0.f;
    float ax = 0.f, ay = 0.f;
    const int c2 = lane * 2;
    for (int j = beg; j < end; ++j) {
        int e = eidx[j];
        int c = col[e];
        float x = sd + s_src[c];
        x = (x > 0.f) ? x : SLOPE * x;
        float w = __expf(x - m);
        wsum += w;
        float2 v = *reinterpret_cast<const float2*>(&Wh[(size_t)c * 128 + c2]);
        ax = fmaf(w, v.x, ax);
        ay = fmaf(w, v.y, ay);
    }
    float inv = 1.f / fmaxf(wsum, 1e-12f);
    float2* o = reinterpret_cast<float2*>(&out[(size_t)wid * 128 + c2]);
    float2 cur = *o;
    cur.x += ax * inv;
    cur.y += ay * inv;
    *o = cur;
}

// ---------------- launch ----------------
extern "C" void kernel_launch(void* const* d_in, const int* in_sizes, int n_in,
                              void* d_out, int out_size, void* d_ws, size_t ws_size,
                              hipStream_t stream) {
    const float* H = (const float*)d_in[0];
    const int* row[3] = {(const int*)d_in[1], (const int*)d_in[5], (const int*)d_in[9]};
    const int* col[3] = {(const int*)d_in[2], (const int*)d_in[6], (const int*)d_in[10]};
    const float* W[3] = {(const float*)d_in[3], (const float*)d_in[7], (const float*)d_in[11]};
    const float* a[3] = {(const float*)d_in[4], (const float*)d_in[8], (const float*)d_in[12]};
    const float* bias = (const float*)d_in[13];

    const int N = in_sizes[0] / 128;
    const int E = in_sizes[1];
    float* out = (float*)d_out;

    char* ws = (char*)d_ws;
    size_t off = 0;
    auto alloc = [&](size_t bytes) -> void* {
        void* p = ws + off;
        off += (bytes + 255) & ~(size_t)255;
        return p;
    };
    float* Wh = (float*)alloc((size_t)N * 128 * 4);
    float* sd = (float*)alloc((size_t)N * 4);
    float* ss = (float*)alloc((size_t)N * 4);
    int* offs = (int*)alloc((size_t)(N + 1) * 4);  // counts -> exclusive offsets
    int* cursor = (int*)alloc((size_t)N * 4);
    int* bsum = (int*)alloc(4096 * 4);
    int* eidx = (int*)alloc((size_t)E * 4);

    const int nbN = (N + 255) / 256;       // blocks over nodes
    const int nbE = (E + 255) / 256;       // blocks over edges
    const int nbW = (N + 3) / 4;           // wave-per-node blocks (4 waves/block)
    const int nbG = (N + 63) / 64;         // gemm blocks

    init_out<<<(N * 128 + 255) / 256, 256, 0, stream>>>(out, bias, N * 128);

    for (int r = 0; r < 3; ++r) {
        gemm_wh<<<nbG, 256, 0, stream>>>(H, W[r], Wh, N);
        scores<<<nbW, 256, 0, stream>>>(Wh, a[r], sd, ss, N);

        hipMemsetAsync(offs, 0, (size_t)(N + 1) * 4, stream);
        hist<<<nbE, 256, 0, stream>>>(row[r], offs, E);
        scan1<<<nbN, 256, 0, stream>>>(offs, bsum, N);
        scan2<<<1, 512, 0, stream>>>(bsum, nbN);
        scan3<<<nbN, 256, 0, stream>>>(offs, bsum, N, E);

        hipMemcpyAsync(cursor, offs, (size_t)N * 4, hipMemcpyDeviceToDevice, stream);
        scatter<<<nbE, 256, 0, stream>>>(row[r], cursor, eidx, E);

        aggregate<<<nbW, 256, 0, stream>>>(Wh, sd, ss, col[r], offs, eidx, out, N);
    }
}

// Round 2
// 728.652 us; speedup vs baseline: 1.6004x; 1.6004x over previous
//
#include <hip/hip_runtime.h>

#define SLOPE 0.2f

typedef unsigned int uint;
typedef unsigned short ushort;

__device__ inline ushort f2bf(float f) {
    uint u = __float_as_uint(f);
    uint r = (u + 0x7FFFu + ((u >> 16) & 1u)) >> 16;
    return (ushort)r;
}

// ---------------- init output with bias (fallback path only) ----------------
__global__ void init_out(float* __restrict__ out, const float* __restrict__ bias, int total) {
    int i = blockIdx.x * blockDim.x + threadIdx.x;
    if (i < total) out[i] = bias[i & 127];
}

// ---------------- fused GEMM + scores: Wh(bf16) = H @ W ; sd = Wh.a[:128]; ss = Wh.a[128:]
// Block: 256 threads, tile 64 rows x 128 cols. H tile transposed in LDS.
__global__ __launch_bounds__(256) void gemm_wh(const float* __restrict__ H,
                                               const float* __restrict__ W,
                                               const float* __restrict__ a,
                                               ushort* __restrict__ Wh,
                                               float* __restrict__ sd,
                                               float* __restrict__ ss, int N) {
    __shared__ float HT[128][66];
    const int brow = blockIdx.x * 64;
    const int t = threadIdx.x;

    for (int i = t; i < 64 * 128; i += 256) {
        int r = i >> 7, k = i & 127;
        int gr = brow + r;
        HT[k][r] = (gr < N) ? H[(size_t)gr * 128 + k] : 0.f;
    }
    __syncthreads();

    const int tc = (t & 31) * 4;   // 4 consecutive cols
    const int tr = (t >> 5) * 8;   // 8 consecutive rows
    float acc[8][4];
#pragma unroll
    for (int i = 0; i < 8; ++i)
#pragma unroll
        for (int j = 0; j < 4; ++j) acc[i][j] = 0.f;

    for (int k = 0; k < 128; ++k) {
        float4 w = *reinterpret_cast<const float4*>(&W[k * 128 + tc]);
        float h[8];
#pragma unroll
        for (int i = 0; i < 8; i += 2) {
            float2 h2 = *reinterpret_cast<const float2*>(&HT[k][tr + i]);
            h[i] = h2.x; h[i + 1] = h2.y;
        }
#pragma unroll
        for (int i = 0; i < 8; ++i) {
            acc[i][0] = fmaf(h[i], w.x, acc[i][0]);
            acc[i][1] = fmaf(h[i], w.y, acc[i][1]);
            acc[i][2] = fmaf(h[i], w.z, acc[i][2]);
            acc[i][3] = fmaf(h[i], w.w, acc[i][3]);
        }
    }

    const float4 aL = *reinterpret_cast<const float4*>(&a[tc]);
    const float4 aR = *reinterpret_cast<const float4*>(&a[128 + tc]);

#pragma unroll
    for (int i = 0; i < 8; ++i) {
        int gr = brow + tr + i;
        // score partials for this row, reduce over the 32-thread row group
        float pd = acc[i][0] * aL.x + acc[i][1] * aL.y + acc[i][2] * aL.z + acc[i][3] * aL.w;
        float ps = acc[i][0] * aR.x + acc[i][1] * aR.y + acc[i][2] * aR.z + acc[i][3] * aR.w;
#pragma unroll
        for (int off = 16; off; off >>= 1) {
            pd += __shfl_xor(pd, off);
            ps += __shfl_xor(ps, off);
        }
        if (gr < N) {
            if ((t & 31) == 0) { sd[gr] = pd; ss[gr] = ps; }
            *reinterpret_cast<ushort4*>(&Wh[(size_t)gr * 128 + tc]) =
                make_ushort4(f2bf(acc[i][0]), f2bf(acc[i][1]), f2bf(acc[i][2]), f2bf(acc[i][3]));
        }
    }
}

// ---------------- histogram of destination rows ----------------
__global__ void hist(const int* __restrict__ row, int* __restrict__ cnt, int E) {
    int i = blockIdx.x * blockDim.x + threadIdx.x;
    if (i < E) atomicAdd(&cnt[row[i]], 1);
}

// ---------------- 3-kernel exclusive scan ----------------
__global__ __launch_bounds__(256) void scan1(int* __restrict__ data, int* __restrict__ bsum, int N) {
    __shared__ int s[256];
    int i = blockIdx.x * 256 + threadIdx.x;
    int v = (i < N) ? data[i] : 0;
    s[threadIdx.x] = v;
    __syncthreads();
    for (int off = 1; off < 256; off <<= 1) {
        int y = (threadIdx.x >= off) ? s[threadIdx.x - off] : 0;
        __syncthreads();
        s[threadIdx.x] += y;
        __syncthreads();
    }
    if (i < N) data[i] = s[threadIdx.x] - v;
    if (threadIdx.x == 255) bsum[blockIdx.x] = s[255];
}

__global__ __launch_bounds__(512) void scan2(int* __restrict__ bsum, int nb) {
    __shared__ int s[512];
    int t = threadIdx.x;
    int v = (t < nb) ? bsum[t] : 0;
    s[t] = v;
    __syncthreads();
    for (int off = 1; off < 512; off <<= 1) {
        int y = (t >= off) ? s[t - off] : 0;
        __syncthreads();
        s[t] += y;
        __syncthreads();
    }
    if (t < nb) bsum[t] = s[t] - v;
}

__global__ void scan3(int* __restrict__ offs, const int* __restrict__ bsum, int N, int E) {
    int i = blockIdx.x * blockDim.x + threadIdx.x;
    if (i < N) offs[i] += bsum[i >> 8];
    if (i == 0) offs[N] = E;
}

// ---------------- scatter: build CSR-ordered e (leaky score) and col ----------------
__global__ void scatter2(const int* __restrict__ row, const int* __restrict__ col,
                         const float* __restrict__ sd, const float* __restrict__ ss,
                         int* __restrict__ cursor,
                         float* __restrict__ e_csr, int* __restrict__ col_csr, int E) {
    int i = blockIdx.x * blockDim.x + threadIdx.x;
    if (i < E) {
        int rr = row[i], cc = col[i];
        float x = sd[rr] + ss[cc];
        x = (x > 0.f) ? x : SLOPE * x;
        int pos = atomicAdd(&cursor[rr], 1);
        e_csr[pos] = x;
        col_csr[pos] = cc;
    }
}

// ---------------- fused aggregation over up-to-3 relations, one wave per node ----------------
struct AggPtrs {
    const uint* wh[3];     // bf16x2-packed Wh, 64 uints per row
    const float* e[3];     // CSR-ordered leaky scores
    const int* col[3];     // CSR-ordered cols
    const int* offs[3];
};

__global__ __launch_bounds__(256) void aggregate3(AggPtrs p, int nrel,
                                                  const float* __restrict__ bias,
                                                  float* __restrict__ out, int N, int accum) {
    int wid = (int)((blockIdx.x * 256 + threadIdx.x) >> 6);
    int lane = threadIdx.x & 63;
    if (wid >= N) return;
    const int half = lane >> 5;
    const int hl = lane & 31;
    const int c4 = hl * 4;

    float acc0 = 0.f, acc1 = 0.f, acc2 = 0.f, acc3 = 0.f;

    for (int r = 0; r < nrel; ++r) {
        int beg = p.offs[r][wid], end = p.offs[r][wid + 1];
        int cnt = end - beg;
        if (cnt <= 0) continue;
        const float* e = p.e[r] + beg;
        const int* col = p.col[r] + beg;
        const uint* wh = p.wh[r];

        // pass 1: max over coalesced CSR-ordered scores
        float m = -1e30f;
        for (int j = lane; j < cnt; j += 64) m = fmaxf(m, e[j]);
#pragma unroll
        for (int off = 32; off; off >>= 1) m = fmaxf(m, __shfl_xor(m, off));

        // pass 2: 2 edges per iteration (one per half-wave), lane owns 4 cols
        float wsum = 0.f;
        float a0 = 0.f, a1 = 0.f, a2 = 0.f, a3 = 0.f;
        for (int j = half; j < cnt; j += 2) {
            float w = __expf(e[j] - m);
            wsum += w;
            int c = col[j];
            uint2 v = *reinterpret_cast<const uint2*>(wh + (size_t)c * 64 + hl * 2);
            float f0 = __uint_as_float(v.x << 16);
            float f1 = __uint_as_float(v.x & 0xFFFF0000u);
            float f2 = __uint_as_float(v.y << 16);
            float f3 = __uint_as_float(v.y & 0xFFFF0000u);
            a0 = fmaf(w, f0, a0);
            a1 = fmaf(w, f1, a1);
            a2 = fmaf(w, f2, a2);
            a3 = fmaf(w, f3, a3);
        }
        // merge halves (both halves own the same 4 cols)
        wsum += __shfl_xor(wsum, 32);
        a0 += __shfl_xor(a0, 32);
        a1 += __shfl_xor(a1, 32);
        a2 += __shfl_xor(a2, 32);
        a3 += __shfl_xor(a3, 32);
        float inv = 1.f / fmaxf(wsum, 1e-12f);
        acc0 = fmaf(a0, inv, acc0);
        acc1 = fmaf(a1, inv, acc1);
        acc2 = fmaf(a2, inv, acc2);
        acc3 = fmaf(a3, inv, acc3);
    }

    if (half == 0) {
        float4* o = reinterpret_cast<float4*>(&out[(size_t)wid * 128 + c4]);
        if (accum) {
            float4 cur = *o;
            *o = make_float4(cur.x + acc0, cur.y + acc1, cur.z + acc2, cur.w + acc3);
        } else {
            float4 b = *reinterpret_cast<const float4*>(&bias[c4]);
            *o = make_float4(b.x + acc0, b.y + acc1, b.z + acc2, b.w + acc3);
        }
    }
}

// ---------------- launch ----------------
extern "C" void kernel_launch(void* const* d_in, const int* in_sizes, int n_in,
                              void* d_out, int out_size, void* d_ws, size_t ws_size,
                              hipStream_t stream) {
    const float* H = (const float*)d_in[0];
    const int* row[3] = {(const int*)d_in[1], (const int*)d_in[5], (const int*)d_in[9]};
    const int* col[3] = {(const int*)d_in[2], (const int*)d_in[6], (const int*)d_in[10]};
    const float* W[3] = {(const float*)d_in[3], (const float*)d_in[7], (const float*)d_in[11]};
    const float* a[3] = {(const float*)d_in[4], (const float*)d_in[8], (const float*)d_in[12]};
    const float* bias = (const float*)d_in[13];

    const int N = in_sizes[0] / 128;
    const int E = in_sizes[1];
    float* out = (float*)d_out;

    const int nbN = (N + 255) / 256;
    const int nbE = (E + 255) / 256;
    const int nbW = (N + 3) / 4;
    const int nbG = (N + 63) / 64;

    char* ws = (char*)d_ws;
    size_t off = 0;
    auto alloc = [&](size_t bytes) -> void* {
        void* p = ws + off;
        off += (bytes + 255) & ~(size_t)255;
        return p;
    };

    const size_t whB = (size_t)N * 128 * 2;       // bf16 Wh per relation
    const size_t fused_need = 3 * (whB + 2 * (size_t)N * 4 + (size_t)(N + 1) * 4 +
                                   2 * (size_t)E * 4) +
                              (size_t)N * 4 + 4096 * 4 + 8 * 256;

    if (ws_size >= fused_need) {
        // ---------- fully fused path ----------
        ushort* Wh[3]; float* sd[3]; float* ss[3]; int* offs[3]; float* e_csr[3]; int* col_csr[3];
        for (int r = 0; r < 3; ++r) Wh[r] = (ushort*)alloc(whB);
        for (int r = 0; r < 3; ++r) { sd[r] = (float*)alloc((size_t)N * 4); ss[r] = (float*)alloc((size_t)N * 4); }
        for (int r = 0; r < 3; ++r) offs[r] = (int*)alloc((size_t)(N + 1) * 4);
        for (int r = 0; r < 3; ++r) { e_csr[r] = (float*)alloc((size_t)E * 4); col_csr[r] = (int*)alloc((size_t)E * 4); }
        int* cursor = (int*)alloc((size_t)N * 4);
        int* bsum = (int*)alloc(4096 * 4);

        for (int r = 0; r < 3; ++r) {
            gemm_wh<<<nbG, 256, 0, stream>>>(H, W[r], a[r], Wh[r], sd[r], ss[r], N);
            hipMemsetAsync(offs[r], 0, (size_t)(N + 1) * 4, stream);
            hist<<<nbE, 256, 0, stream>>>(row[r], offs[r], E);
            scan1<<<nbN, 256, 0, stream>>>(offs[r], bsum, N);
            scan2<<<1, 512, 0, stream>>>(bsum, nbN);
            scan3<<<nbN, 256, 0, stream>>>(offs[r], bsum, N, E);
            hipMemcpyAsync(cursor, offs[r], (size_t)N * 4, hipMemcpyDeviceToDevice, stream);
            scatter2<<<nbE, 256, 0, stream>>>(row[r], col[r], sd[r], ss[r], cursor,
                                              e_csr[r], col_csr[r], E);
        }
        AggPtrs p;
        for (int r = 0; r < 3; ++r) {
            p.wh[r] = (const uint*)Wh[r];
            p.e[r] = e_csr[r];
            p.col[r] = col_csr[r];
            p.offs[r] = offs[r];
        }
        aggregate3<<<nbW, 256, 0, stream>>>(p, 3, bias, out, N, 0);
    } else {
        // ---------- sequential fallback (shared buffers) ----------
        ushort* Wh = (ushort*)alloc(whB);
        float* sd = (float*)alloc((size_t)N * 4);
        float* ss = (float*)alloc((size_t)N * 4);
        int* offs = (int*)alloc((size_t)(N + 1) * 4);
        float* e_csr = (float*)alloc((size_t)E * 4);
        int* col_csr = (int*)alloc((size_t)E * 4);
        int* cursor = (int*)alloc((size_t)N * 4);
        int* bsum = (int*)alloc(4096 * 4);

        init_out<<<(N * 128 + 255) / 256, 256, 0, stream>>>(out, bias, N * 128);
        for (int r = 0; r < 3; ++r) {
            gemm_wh<<<nbG, 256, 0, stream>>>(H, W[r], a[r], Wh, sd, ss, N);
            hipMemsetAsync(offs, 0, (size_t)(N + 1) * 4, stream);
            hist<<<nbE, 256, 0, stream>>>(row[r], offs, E);
            scan1<<<nbN, 256, 0, stream>>>(offs, bsum, N);
            scan2<<<1, 512, 0, stream>>>(bsum, nbN);
            scan3<<<nbN, 256, 0, stream>>>(offs, bsum, N, E);
            hipMemcpyAsync(cursor, offs, (size_t)N * 4, hipMemcpyDeviceToDevice, stream);
            scatter2<<<nbE, 256, 0, stream>>>(row[r], col[r], sd, ss, cursor,
                                              e_csr, col_csr, E);
            AggPtrs p;
            p.wh[0] = (const uint*)Wh; p.e[0] = e_csr; p.col[0] = col_csr; p.offs[0] = offs;
            p.wh[1] = p.wh[2] = nullptr; p.e[1] = p.e[2] = nullptr;
            p.col[1] = p.col[2] = nullptr; p.offs[1] = p.offs[2] = nullptr;
            aggregate3<<<nbW, 256, 0, stream>>>(p, 1, nullptr, out, N, 1);
        }
    }
}

// Round 3
// 507.817 us; speedup vs baseline: 2.2964x; 1.4349x over previous
//
#include <hip/hip_runtime.h>

#define SLOPE 0.2f

typedef unsigned int uint;
typedef unsigned short ushort;
typedef __attribute__((ext_vector_type(8))) short short8;
typedef __attribute__((ext_vector_type(4))) float f32x4;

__device__ inline ushort f2bf(float f) {
    uint u = __float_as_uint(f);
    uint r = (u + 0x7FFFu + ((u >> 16) & 1u)) >> 16;
    return (ushort)r;
}
__device__ inline uint pack2bf(float lo, float hi) {
    return (uint)f2bf(lo) | ((uint)f2bf(hi) << 16);
}
__device__ inline float bfl(uint u) { return __uint_as_float(u << 16); }
__device__ inline float bfh(uint u) { return __uint_as_float(u & 0xFFFF0000u); }

// ---------------- W -> WT bf16 transposed [n][k], 3 relations ----------------
__global__ void wt3(const float* __restrict__ W0, const float* __restrict__ W1,
                    const float* __restrict__ W2, ushort* __restrict__ WT) {
    int r = blockIdx.x;
    const float* W = (r == 0) ? W0 : (r == 1) ? W1 : W2;
    ushort* wt = WT + r * 16384;
    for (int i = threadIdx.x; i < 16384; i += 256) {
        int k = i >> 7, n = i & 127;
        wt[n * 128 + k] = f2bf(W[i]);
    }
}

// ---------------- MFMA GEMM: Wh_r(bf16) = H @ W_r, 128 rows/block, grid.y = rel ----
__global__ __launch_bounds__(256) void gemm3(const float* __restrict__ H,
                                             const ushort* __restrict__ WT,
                                             ushort* __restrict__ Wh0,
                                             ushort* __restrict__ Wh1,
                                             ushort* __restrict__ Wh2, int N) {
    __shared__ ushort lds[16384];  // 128 rows x 128 bf16, XOR-swizzled
    const int rel = blockIdx.y;
    ushort* Wh = (rel == 0) ? Wh0 : (rel == 1) ? Wh1 : Wh2;
    const ushort* wt = WT + rel * 16384;
    const int brow = blockIdx.x * 128;
    const int t = threadIdx.x;

    // stage H tile: fp32 -> bf16, swizzled LDS. 2048 chunks of 16B, 8 per thread.
    for (int c = t; c < 2048; c += 256) {
        int r = c >> 4;
        int kb = (c & 15) << 4;            // byte offset in bf16 row
        int gr = brow + r;
        uint4 u = make_uint4(0, 0, 0, 0);
        if (gr < N) {
            const float* hp = H + (size_t)gr * 128 + (kb >> 1);
            float4 v0 = *reinterpret_cast<const float4*>(hp);
            float4 v1 = *reinterpret_cast<const float4*>(hp + 4);
            u.x = pack2bf(v0.x, v0.y);
            u.y = pack2bf(v0.z, v0.w);
            u.z = pack2bf(v1.x, v1.y);
            u.w = pack2bf(v1.z, v1.w);
        }
        int dst = (r << 8) + (kb ^ ((r & 7) << 4));
        *reinterpret_cast<uint4*>((char*)lds + dst) = u;
    }
    __syncthreads();

    const int wave = t >> 6, lane = t & 63;
    const int l16 = lane & 15, lhi = lane >> 4;

    // B fragments: 2 n-tiles x 4 k-steps, from transposed bf16 W (L2-hot)
    short8 bf[2][4];
#pragma unroll
    for (int nt = 0; nt < 2; ++nt) {
        int n = wave * 32 + nt * 16 + l16;
#pragma unroll
        for (int ks = 0; ks < 4; ++ks) {
            int k = ks * 32 + lhi * 8;
            bf[nt][ks] = *reinterpret_cast<const short8*>(wt + n * 128 + k);
        }
    }

    f32x4 acc[8][2];
#pragma unroll
    for (int mt = 0; mt < 8; ++mt) {
        acc[mt][0] = (f32x4)(0.f);
        acc[mt][1] = (f32x4)(0.f);
    }

#pragma unroll
    for (int ks = 0; ks < 4; ++ks) {
#pragma unroll
        for (int mt = 0; mt < 8; ++mt) {
            int r = mt * 16 + l16;
            int kb = (ks * 32 + lhi * 8) * 2;
            int addr = (r << 8) + (kb ^ ((r & 7) << 4));
            short8 af = *reinterpret_cast<const short8*>((char*)lds + addr);
            acc[mt][0] = __builtin_amdgcn_mfma_f32_16x16x32_bf16(af, bf[0][ks], acc[mt][0], 0, 0, 0);
            acc[mt][1] = __builtin_amdgcn_mfma_f32_16x16x32_bf16(af, bf[1][ks], acc[mt][1], 0, 0, 0);
        }
    }

    // D: row = mt*16 + lhi*4 + reg, col = wave*32 + nt*16 + l16
#pragma unroll
    for (int mt = 0; mt < 8; ++mt)
#pragma unroll
        for (int nt = 0; nt < 2; ++nt)
#pragma unroll
            for (int reg = 0; reg < 4; ++reg) {
                int gr = brow + mt * 16 + lhi * 4 + reg;
                if (gr < N)
                    Wh[(size_t)gr * 128 + wave * 32 + nt * 16 + l16] = f2bf(acc[mt][nt][reg]);
            }
}

// ---------------- scores: quarter-wave per node, 3 relations ----------------
__global__ __launch_bounds__(256) void scores_k(const uint* __restrict__ wh0,
                                                const uint* __restrict__ wh1,
                                                const uint* __restrict__ wh2,
                                                const float* __restrict__ a0,
                                                const float* __restrict__ a1,
                                                const float* __restrict__ a2,
                                                float* __restrict__ sd,
                                                float* __restrict__ ss, int N) {
    int node = blockIdx.x * 16 + (threadIdx.x >> 4);
    int ql = threadIdx.x & 15;
    if (node >= N) return;
#pragma unroll
    for (int r = 0; r < 3; ++r) {
        const uint* wh = (r == 0) ? wh0 : (r == 1) ? wh1 : wh2;
        const float* a = (r == 0) ? a0 : (r == 1) ? a1 : a2;
        const uint4 v = reinterpret_cast<const uint4*>(wh + ((size_t)node << 6))[ql];
        float f0 = bfl(v.x), f1 = bfh(v.x), f2 = bfl(v.y), f3 = bfh(v.y);
        float f4 = bfl(v.z), f5 = bfh(v.z), f6 = bfl(v.w), f7 = bfh(v.w);
        float4 aL0 = *reinterpret_cast<const float4*>(a + ql * 8);
        float4 aL1 = *reinterpret_cast<const float4*>(a + ql * 8 + 4);
        float4 aR0 = *reinterpret_cast<const float4*>(a + 128 + ql * 8);
        float4 aR1 = *reinterpret_cast<const float4*>(a + 128 + ql * 8 + 4);
        float pd = f0 * aL0.x + f1 * aL0.y + f2 * aL0.z + f3 * aL0.w +
                   f4 * aL1.x + f5 * aL1.y + f6 * aL1.z + f7 * aL1.w;
        float ps = f0 * aR0.x + f1 * aR0.y + f2 * aR0.z + f3 * aR0.w +
                   f4 * aR1.x + f5 * aR1.y + f6 * aR1.z + f7 * aR1.w;
#pragma unroll
        for (int off = 1; off < 16; off <<= 1) {
            pd += __shfl_xor(pd, off);
            ps += __shfl_xor(ps, off);
        }
        if (ql == 0) { sd[r * N + node] = pd; ss[r * N + node] = ps; }
    }
}

// ---------------- histogram over concatenated (rel,node) ----------------
__global__ void hist3(const int* __restrict__ r0, const int* __restrict__ r1,
                      const int* __restrict__ r2, int* __restrict__ cnt, int E, int N) {
    int i = blockIdx.x * 256 + threadIdx.x;
    if (i >= 3 * E) return;
    int r = (i >= 2 * E) ? 2 : (i >= E) ? 1 : 0;
    int li = i - r * E;
    const int* rp = (r == 0) ? r0 : (r == 1) ? r1 : r2;
    atomicAdd(&cnt[r * N + rp[li]], 1);
}

// ---------------- 2-level exclusive scan over 3N ----------------
__global__ __launch_bounds__(256) void scan1(int* __restrict__ data, int* __restrict__ bsum, int L) {
    __shared__ int s[256];
    int i = blockIdx.x * 256 + threadIdx.x;
    int v = (i < L) ? data[i] : 0;
    s[threadIdx.x] = v;
    __syncthreads();
    for (int off = 1; off < 256; off <<= 1) {
        int y = (threadIdx.x >= off) ? s[threadIdx.x - off] : 0;
        __syncthreads();
        s[threadIdx.x] += y;
        __syncthreads();
    }
    if (i < L) data[i] = s[threadIdx.x] - v;
    if (threadIdx.x == 255) bsum[blockIdx.x] = s[255];
}

__global__ __launch_bounds__(1024) void scan2(int* __restrict__ bsum, int nb) {
    __shared__ int s[1024];
    int t = threadIdx.x;
    int carry = 0;
    for (int base = 0; base < nb; base += 1024) {
        int i = base + t;
        int v = (i < nb) ? bsum[i] : 0;
        s[t] = v;
        __syncthreads();
        for (int off = 1; off < 1024; off <<= 1) {
            int y = (t >= off) ? s[t - off] : 0;
            __syncthreads();
            s[t] += y;
            __syncthreads();
        }
        if (i < nb) bsum[i] = s[t] - v + carry;
        carry += s[1023];
        __syncthreads();
    }
}

__global__ void scan3(int* __restrict__ offs, const int* __restrict__ bsum, int L) {
    int i = blockIdx.x * 256 + threadIdx.x;
    if (i < L) offs[i] += bsum[i >> 8];
}

// ---------------- scatter: CSR-ordered (w=exp(leaky(e)), col); offs doubles as cursor ----
__global__ void scatter3(const int* __restrict__ r0, const int* __restrict__ r1,
                         const int* __restrict__ r2, const int* __restrict__ c0,
                         const int* __restrict__ c1, const int* __restrict__ c2,
                         const float* __restrict__ sd, const float* __restrict__ ss,
                         int* __restrict__ offs, uint2* __restrict__ wc, int E, int N) {
    int i = blockIdx.x * 256 + threadIdx.x;
    if (i >= 3 * E) return;
    int r = (i >= 2 * E) ? 2 : (i >= E) ? 1 : 0;
    int li = i - r * E;
    const int* rp = (r == 0) ? r0 : (r == 1) ? r1 : r2;
    const int* cp = (r == 0) ? c0 : (r == 1) ? c1 : c2;
    int rr = rp[li], cc = cp[li];
    float x = sd[r * N + rr] + ss[r * N + cc];
    x = (x > 0.f) ? x : SLOPE * x;
    float w = __expf(x);
    int pos = atomicAdd(&offs[r * N + rr], 1);
    wc[pos] = make_uint2(__float_as_uint(w), (uint)cc);
}

// ---------------- aggregation: quarter-wave per node, no reductions ----------------
__global__ __launch_bounds__(256) void aggregate3(const uint* __restrict__ wh0,
                                                  const uint* __restrict__ wh1,
                                                  const uint* __restrict__ wh2,
                                                  const uint2* __restrict__ wc,
                                                  const int* __restrict__ offs,
                                                  const float* __restrict__ bias,
                                                  float* __restrict__ out, int N) {
    int node = blockIdx.x * 16 + (threadIdx.x >> 4);
    int ql = threadIdx.x & 15;
    if (node >= N) return;

    float t0 = 0.f, t1 = 0.f, t2 = 0.f, t3 = 0.f, t4 = 0.f, t5 = 0.f, t6 = 0.f, t7 = 0.f;

#pragma unroll
    for (int r = 0; r < 3; ++r) {
        const uint* wh = (r == 0) ? wh0 : (r == 1) ? wh1 : wh2;
        int idx = r * N + node;
        int end = offs[idx];                       // post-scatter: end of bucket
        int beg = (idx == 0) ? 0 : offs[idx - 1];  // previous bucket's end
        if (beg >= end) continue;
        float wsum = 0.f;
        float a0 = 0.f, a1 = 0.f, a2 = 0.f, a3 = 0.f, a4 = 0.f, a5 = 0.f, a6 = 0.f, a7 = 0.f;
        for (int j = beg; j < end; ++j) {
            uint2 e = wc[j];
            float w = __uint_as_float(e.x);
            int c = (int)e.y;
            uint4 v = reinterpret_cast<const uint4*>(wh + ((size_t)c << 6))[ql];
            wsum += w;
            a0 = fmaf(w, bfl(v.x), a0);
            a1 = fmaf(w, bfh(v.x), a1);
            a2 = fmaf(w, bfl(v.y), a2);
            a3 = fmaf(w, bfh(v.y), a3);
            a4 = fmaf(w, bfl(v.z), a4);
            a5 = fmaf(w, bfh(v.z), a5);
            a6 = fmaf(w, bfl(v.w), a6);
            a7 = fmaf(w, bfh(v.w), a7);
        }
        float inv = 1.f / fmaxf(wsum, 1e-12f);
        t0 = fmaf(a0, inv, t0); t1 = fmaf(a1, inv, t1);
        t2 = fmaf(a2, inv, t2); t3 = fmaf(a3, inv, t3);
        t4 = fmaf(a4, inv, t4); t5 = fmaf(a5, inv, t5);
        t6 = fmaf(a6, inv, t6); t7 = fmaf(a7, inv, t7);
    }

    float4 b0 = *reinterpret_cast<const float4*>(bias + ql * 8);
    float4 b1 = *reinterpret_cast<const float4*>(bias + ql * 8 + 4);
    float* o = out + (size_t)node * 128 + ql * 8;
    *reinterpret_cast<float4*>(o) = make_float4(t0 + b0.x, t1 + b0.y, t2 + b0.z, t3 + b0.w);
    *reinterpret_cast<float4*>(o + 4) = make_float4(t4 + b1.x, t5 + b1.y, t6 + b1.z, t7 + b1.w);
}

// ---------------- launch ----------------
extern "C" void kernel_launch(void* const* d_in, const int* in_sizes, int n_in,
                              void* d_out, int out_size, void* d_ws, size_t ws_size,
                              hipStream_t stream) {
    const float* H = (const float*)d_in[0];
    const int* row[3] = {(const int*)d_in[1], (const int*)d_in[5], (const int*)d_in[9]};
    const int* col[3] = {(const int*)d_in[2], (const int*)d_in[6], (const int*)d_in[10]};
    const float* W[3] = {(const float*)d_in[3], (const float*)d_in[7], (const float*)d_in[11]};
    const float* a[3] = {(const float*)d_in[4], (const float*)d_in[8], (const float*)d_in[12]};
    const float* bias = (const float*)d_in[13];

    const int N = in_sizes[0] / 128;
    const int E = in_sizes[1];
    float* out = (float*)d_out;

    char* ws = (char*)d_ws;
    size_t off = 0;
    auto alloc = [&](size_t bytes) -> void* {
        void* p = ws + off;
        off += (bytes + 255) & ~(size_t)255;
        return p;
    };

    ushort* WT = (ushort*)alloc(3 * 16384 * 2);
    ushort* Wh[3];
    for (int r = 0; r < 3; ++r) Wh[r] = (ushort*)alloc((size_t)N * 128 * 2);
    float* sd = (float*)alloc((size_t)3 * N * 4);
    float* ss = (float*)alloc((size_t)3 * N * 4);
    int* offs = (int*)alloc((size_t)3 * N * 4);
    int* bsum = (int*)alloc(8192);
    uint2* wc = (uint2*)alloc((size_t)3 * E * 8);

    const int L = 3 * N;
    const int nbL = (L + 255) / 256;
    const int nb3E = (3 * E + 255) / 256;
    const int nbG = (N + 127) / 128;
    const int nbQ = (N + 15) / 16;

    wt3<<<3, 256, 0, stream>>>(W[0], W[1], W[2], WT);
    gemm3<<<dim3(nbG, 3), 256, 0, stream>>>(H, WT, Wh[0], Wh[1], Wh[2], N);
    scores_k<<<nbQ, 256, 0, stream>>>((const uint*)Wh[0], (const uint*)Wh[1], (const uint*)Wh[2],
                                      a[0], a[1], a[2], sd, ss, N);

    hipMemsetAsync(offs, 0, (size_t)L * 4, stream);
    hist3<<<nb3E, 256, 0, stream>>>(row[0], row[1], row[2], offs, E, N);
    scan1<<<nbL, 256, 0, stream>>>(offs, bsum, L);
    scan2<<<1, 1024, 0, stream>>>(bsum, nbL);
    scan3<<<nbL, 256, 0, stream>>>(offs, bsum, L);

    scatter3<<<nb3E, 256, 0, stream>>>(row[0], row[1], row[2], col[0], col[1], col[2],
                                       sd, ss, offs, wc, E, N);
    aggregate3<<<nbQ, 256, 0, stream>>>((const uint*)Wh[0], (const uint*)Wh[1], (const uint*)Wh[2],
                                        wc, offs, bias, out, N);
}

// Round 4
// 341.990 us; speedup vs baseline: 3.4099x; 1.4849x over previous
//
#include <hip/hip_runtime.h>

#define SLOPE 0.2f

typedef unsigned int uint;
typedef unsigned short ushort;
typedef __attribute__((ext_vector_type(8))) short short8;
typedef __attribute__((ext_vector_type(4))) float f32x4;

#define BINW 2048          // idx per coarse bin (idx = rel*N + row)
#define BINSHIFT 11

__device__ inline ushort f2bf(float f) {
    uint u = __float_as_uint(f);
    uint r = (u + 0x7FFFu + ((u >> 16) & 1u)) >> 16;
    return (ushort)r;
}
__device__ inline uint pack2bf(float lo, float hi) {
    return (uint)f2bf(lo) | ((uint)f2bf(hi) << 16);
}
__device__ inline float bfl(uint u) { return __uint_as_float(u << 16); }
__device__ inline float bfh(uint u) { return __uint_as_float(u & 0xFFFF0000u); }

// ---------------- W -> WT bf16 transposed [n][k], 3 relations ----------------
__global__ void wt3(const float* __restrict__ W0, const float* __restrict__ W1,
                    const float* __restrict__ W2, ushort* __restrict__ WT) {
    int r = blockIdx.x;
    const float* W = (r == 0) ? W0 : (r == 1) ? W1 : W2;
    ushort* wt = WT + r * 16384;
    for (int i = threadIdx.x; i < 16384; i += 256) {
        int k = i >> 7, n = i & 127;
        wt[n * 128 + k] = f2bf(W[i]);
    }
}

// ---------------- MFMA GEMM: Wh_r(bf16) = H @ W_r; H tile staged ONCE for 3 rels ----
__global__ __launch_bounds__(256) void gemm3(const float* __restrict__ H,
                                             const ushort* __restrict__ WT,
                                             ushort* __restrict__ Wh0,
                                             ushort* __restrict__ Wh1,
                                             ushort* __restrict__ Wh2, int N) {
    __shared__ ushort lds[16384];  // 128 rows x 128 bf16, XOR-swizzled
    const int brow = blockIdx.x * 128;
    const int t = threadIdx.x;

    for (int c = t; c < 2048; c += 256) {
        int r = c >> 4;
        int kb = (c & 15) << 4;
        int gr = brow + r;
        uint4 u = make_uint4(0, 0, 0, 0);
        if (gr < N) {
            const float* hp = H + (size_t)gr * 128 + (kb >> 1);
            float4 v0 = *reinterpret_cast<const float4*>(hp);
            float4 v1 = *reinterpret_cast<const float4*>(hp + 4);
            u.x = pack2bf(v0.x, v0.y);
            u.y = pack2bf(v0.z, v0.w);
            u.z = pack2bf(v1.x, v1.y);
            u.w = pack2bf(v1.z, v1.w);
        }
        int dst = (r << 8) + (kb ^ ((r & 7) << 4));
        *reinterpret_cast<uint4*>((char*)lds + dst) = u;
    }
    __syncthreads();

    const int wave = t >> 6, lane = t & 63;
    const int l16 = lane & 15, lhi = lane >> 4;

    for (int rel = 0; rel < 3; ++rel) {
        ushort* Wh = (rel == 0) ? Wh0 : (rel == 1) ? Wh1 : Wh2;
        const ushort* wt = WT + rel * 16384;

        short8 bf[2][4];
#pragma unroll
        for (int nt = 0; nt < 2; ++nt) {
            int n = wave * 32 + nt * 16 + l16;
#pragma unroll
            for (int ks = 0; ks < 4; ++ks)
                bf[nt][ks] = *reinterpret_cast<const short8*>(wt + n * 128 + ks * 32 + lhi * 8);
        }

        f32x4 acc[8][2];
#pragma unroll
        for (int mt = 0; mt < 8; ++mt) { acc[mt][0] = (f32x4)(0.f); acc[mt][1] = (f32x4)(0.f); }

#pragma unroll
        for (int ks = 0; ks < 4; ++ks) {
#pragma unroll
            for (int mt = 0; mt < 8; ++mt) {
                int r = mt * 16 + l16;
                int kb = (ks * 32 + lhi * 8) * 2;
                int addr = (r << 8) + (kb ^ ((r & 7) << 4));
                short8 af = *reinterpret_cast<const short8*>((char*)lds + addr);
                acc[mt][0] = __builtin_amdgcn_mfma_f32_16x16x32_bf16(af, bf[0][ks], acc[mt][0], 0, 0, 0);
                acc[mt][1] = __builtin_amdgcn_mfma_f32_16x16x32_bf16(af, bf[1][ks], acc[mt][1], 0, 0, 0);
            }
        }

#pragma unroll
        for (int mt = 0; mt < 8; ++mt)
#pragma unroll
            for (int nt = 0; nt < 2; ++nt)
#pragma unroll
                for (int reg = 0; reg < 4; ++reg) {
                    int gr = brow + mt * 16 + lhi * 4 + reg;
                    if (gr < N)
                        Wh[(size_t)gr * 128 + wave * 32 + nt * 16 + l16] = f2bf(acc[mt][nt][reg]);
                }
    }
}

// ---------------- scores: quarter-wave per node, 3 relations ----------------
__global__ __launch_bounds__(256) void scores_k(const uint* __restrict__ wh0,
                                                const uint* __restrict__ wh1,
                                                const uint* __restrict__ wh2,
                                                const float* __restrict__ a0,
                                                const float* __restrict__ a1,
                                                const float* __restrict__ a2,
                                                float* __restrict__ sd,
                                                float* __restrict__ ss, int N) {
    int node = blockIdx.x * 16 + (threadIdx.x >> 4);
    int ql = threadIdx.x & 15;
    if (node >= N) return;
#pragma unroll
    for (int r = 0; r < 3; ++r) {
        const uint* wh = (r == 0) ? wh0 : (r == 1) ? wh1 : wh2;
        const float* a = (r == 0) ? a0 : (r == 1) ? a1 : a2;
        const uint4 v = reinterpret_cast<const uint4*>(wh + ((size_t)node << 6))[ql];
        float f0 = bfl(v.x), f1 = bfh(v.x), f2 = bfl(v.y), f3 = bfh(v.y);
        float f4 = bfl(v.z), f5 = bfh(v.z), f6 = bfl(v.w), f7 = bfh(v.w);
        float4 aL0 = *reinterpret_cast<const float4*>(a + ql * 8);
        float4 aL1 = *reinterpret_cast<const float4*>(a + ql * 8 + 4);
        float4 aR0 = *reinterpret_cast<const float4*>(a + 128 + ql * 8);
        float4 aR1 = *reinterpret_cast<const float4*>(a + 128 + ql * 8 + 4);
        float pd = f0 * aL0.x + f1 * aL0.y + f2 * aL0.z + f3 * aL0.w +
                   f4 * aL1.x + f5 * aL1.y + f6 * aL1.z + f7 * aL1.w;
        float ps = f0 * aR0.x + f1 * aR0.y + f2 * aR0.z + f3 * aR0.w +
                   f4 * aR1.x + f5 * aR1.y + f6 * aR1.z + f7 * aR1.w;
#pragma unroll
        for (int off = 1; off < 16; off <<= 1) {
            pd += __shfl_xor(pd, off);
            ps += __shfl_xor(ps, off);
        }
        if (ql == 0) { sd[r * N + node] = pd; ss[r * N + node] = ps; }
    }
}

// ---------------- coarse-bin histogram (LDS pre-aggregated) ----------------
__global__ __launch_bounds__(256) void binhist(const int* __restrict__ r0,
                                               const int* __restrict__ r1,
                                               const int* __restrict__ r2,
                                               int* __restrict__ bincnt, int E, int N, int nbins) {
    __shared__ int h[256];
    int t = threadIdx.x;
    h[t] = 0;
    __syncthreads();
    int base = blockIdx.x * 4096;
#pragma unroll
    for (int k = 0; k < 16; ++k) {
        int i = base + k * 256 + t;
        if (i < 3 * E) {
            int r = (i >= 2 * E) ? 2 : (i >= E) ? 1 : 0;
            int li = i - r * E;
            const int* rp = (r == 0) ? r0 : (r == 1) ? r1 : r2;
            int idx = r * N + rp[li];
            atomicAdd(&h[idx >> BINSHIFT], 1);
        }
    }
    __syncthreads();
    if (t < nbins && h[t]) atomicAdd(&bincnt[t], h[t]);
}

// ---------------- bin base scan (single block) ----------------
__global__ __launch_bounds__(256) void binscan(const int* __restrict__ bincnt,
                                               int* __restrict__ binbase,
                                               int* __restrict__ gbincur, int nbins, int total) {
    __shared__ int sA[256], sB[256];
    int t = threadIdx.x;
    int v = (t < nbins) ? bincnt[t] : 0;
    sA[t] = v;
    __syncthreads();
    int* pa = sA; int* pb = sB;
    for (int off = 1; off < 256; off <<= 1) {
        int x = pa[t] + ((t >= off) ? pa[t - off] : 0);
        pb[t] = x;
        __syncthreads();
        int* tmp = pa; pa = pb; pb = tmp;
    }
    if (t < nbins) {
        int excl = pa[t] - v;
        binbase[t] = excl;
        gbincur[t] = excl;
    }
    if (t == 0) binbase[nbins] = total;
}

// ---------------- phase 1: compute w, bin-group records, coalesced flush ----------------
// record: .x = col | (idx_lo << 17), .y = float bits of w
__global__ __launch_bounds__(256) void binscatter(const int* __restrict__ r0, const int* __restrict__ r1,
                                                  const int* __restrict__ r2, const int* __restrict__ c0,
                                                  const int* __restrict__ c1, const int* __restrict__ c2,
                                                  const float* __restrict__ sd, const float* __restrict__ ss,
                                                  int* __restrict__ gbincur, uint2* __restrict__ binned,
                                                  int E, int N, int nbins) {
    __shared__ uint2 staged[4096];
    __shared__ int hist[256], sB[256], curi[256], gbase[256];
    const int t = threadIdx.x;
    hist[t] = 0;
    __syncthreads();

    uint2 rec[16];
    short bn[16];
    const int base = blockIdx.x * 4096;
#pragma unroll
    for (int k = 0; k < 16; ++k) {
        int i = base + k * 256 + t;
        bn[k] = -1;
        if (i < 3 * E) {
            int r = (i >= 2 * E) ? 2 : (i >= E) ? 1 : 0;
            int li = i - r * E;
            const int* rp = (r == 0) ? r0 : (r == 1) ? r1 : r2;
            const int* cp = (r == 0) ? c0 : (r == 1) ? c1 : c2;
            int rr = rp[li], cc = cp[li];
            int idx = r * N + rr;
            int b = idx >> BINSHIFT;
            uint lo = (uint)(idx & (BINW - 1));
            float x = sd[idx] + ss[r * N + cc];
            x = (x > 0.f) ? x : SLOPE * x;
            float w = __expf(x);
            rec[k] = make_uint2((uint)cc | (lo << 17), __float_as_uint(w));
            bn[k] = (short)b;
            atomicAdd(&hist[b], 1);
        }
    }
    __syncthreads();

    // inclusive scan of hist -> hist (256, ping-pong even # iters)
    int v = hist[t];
    int* pa = hist; int* pb = sB;
    for (int off = 1; off < 256; off <<= 1) {
        int x = pa[t] + ((t >= off) ? pa[t - off] : 0);
        pb[t] = x;
        __syncthreads();
        int* tmp = pa; pa = pb; pb = tmp;
    }
    // pa == hist holds inclusive; store excl in sB, cursors in curi
    sB[t] = pa[t] - v;
    curi[t] = pa[t] - v;
    if (t < nbins && v > 0) gbase[t] = atomicAdd(&gbincur[t], v);
    __syncthreads();

#pragma unroll
    for (int k = 0; k < 16; ++k)
        if (bn[k] >= 0) {
            int p = atomicAdd(&curi[bn[k]], 1);
            staged[p] = rec[k];
        }
    __syncthreads();

    // flush contiguous per-bin runs
    const int wave = t >> 6, lane = t & 63;
    for (int b = wave; b < nbins; b += 4) {
        int s = sB[b];
        int len = hist[b] - s;
        if (len <= 0) continue;
        int g = gbase[b];
        for (int j = lane; j < len; j += 64) binned[g + j] = staged[s + j];
    }
}

// ---------------- phase 2: per-bin counting sort -> final CSR wc + offs ----------------
__global__ __launch_bounds__(256) void binsort(const uint2* __restrict__ binned,
                                               const int* __restrict__ binbase,
                                               uint2* __restrict__ wc, int* __restrict__ offs, int L) {
    __shared__ int s1[BINW], s2[BINW];
    const int b = blockIdx.x, t = threadIdx.x;
    const int start = binbase[b], end = binbase[b + 1];
    const int ibase = b << BINSHIFT;
    const int width = min(BINW, L - ibase);

    for (int i = t; i < BINW; i += 256) s1[i] = 0;
    __syncthreads();
    for (int j = start + t; j < end; j += 256) {
        uint lo = (binned[j].x >> 17) & (BINW - 1);
        atomicAdd(&s1[lo], 1);
    }
    __syncthreads();

    // inclusive scan over BINW=2048 (11 iterations, ends in s2)
    int* pa = s1; int* pb = s2;
    for (int off = 1; off < BINW; off <<= 1) {
        for (int i = t; i < BINW; i += 256)
            pb[i] = pa[i] + ((i >= off) ? pa[i - off] : 0);
        __syncthreads();
        int* tmp = pa; pa = pb; pb = tmp;
    }
    // pa holds inclusive scan
    for (int i = t; i < width; i += 256) offs[ibase + i] = start + pa[i];
    for (int i = t; i < BINW; i += 256) pb[i] = i ? pa[i - 1] : 0;  // cursors = exclusive
    __syncthreads();

    for (int j = start + t; j < end; j += 256) {
        uint2 r = binned[j];
        uint lo = (r.x >> 17) & (BINW - 1);
        int p = atomicAdd(&pb[lo], 1);
        wc[start + p] = make_uint2(r.y, r.x & 0x1FFFFu);  // {w bits, col}
    }
}

// ---------------- aggregation: quarter-wave per node ----------------
__global__ __launch_bounds__(256) void aggregate3(const uint* __restrict__ wh0,
                                                  const uint* __restrict__ wh1,
                                                  const uint* __restrict__ wh2,
                                                  const uint2* __restrict__ wc,
                                                  const int* __restrict__ offs,
                                                  const float* __restrict__ bias,
                                                  float* __restrict__ out, int N) {
    int node = blockIdx.x * 16 + (threadIdx.x >> 4);
    int ql = threadIdx.x & 15;
    if (node >= N) return;

    float t0 = 0.f, t1 = 0.f, t2 = 0.f, t3 = 0.f, t4 = 0.f, t5 = 0.f, t6 = 0.f, t7 = 0.f;

#pragma unroll
    for (int r = 0; r < 3; ++r) {
        const uint* wh = (r == 0) ? wh0 : (r == 1) ? wh1 : wh2;
        int idx = r * N + node;
        int end = offs[idx];
        int beg = (idx == 0) ? 0 : offs[idx - 1];
        if (beg >= end) continue;
        float wsum = 0.f;
        float a0 = 0.f, a1 = 0.f, a2 = 0.f, a3 = 0.f, a4 = 0.f, a5 = 0.f, a6 = 0.f, a7 = 0.f;
        for (int j = beg; j < end; ++j) {
            uint2 e = wc[j];
            float w = __uint_as_float(e.x);
            int c = (int)e.y;
            uint4 v = reinterpret_cast<const uint4*>(wh + ((size_t)c << 6))[ql];
            wsum += w;
            a0 = fmaf(w, bfl(v.x), a0);
            a1 = fmaf(w, bfh(v.x), a1);
            a2 = fmaf(w, bfl(v.y), a2);
            a3 = fmaf(w, bfh(v.y), a3);
            a4 = fmaf(w, bfl(v.z), a4);
            a5 = fmaf(w, bfh(v.z), a5);
            a6 = fmaf(w, bfl(v.w), a6);
            a7 = fmaf(w, bfh(v.w), a7);
        }
        float inv = 1.f / fmaxf(wsum, 1e-12f);
        t0 = fmaf(a0, inv, t0); t1 = fmaf(a1, inv, t1);
        t2 = fmaf(a2, inv, t2); t3 = fmaf(a3, inv, t3);
        t4 = fmaf(a4, inv, t4); t5 = fmaf(a5, inv, t5);
        t6 = fmaf(a6, inv, t6); t7 = fmaf(a7, inv, t7);
    }

    float4 b0 = *reinterpret_cast<const float4*>(bias + ql * 8);
    float4 b1 = *reinterpret_cast<const float4*>(bias + ql * 8 + 4);
    float* o = out + (size_t)node * 128 + ql * 8;
    *reinterpret_cast<float4*>(o) = make_float4(t0 + b0.x, t1 + b0.y, t2 + b0.z, t3 + b0.w);
    *reinterpret_cast<float4*>(o + 4) = make_float4(t4 + b1.x, t5 + b1.y, t6 + b1.z, t7 + b1.w);
}

// ---------------- launch ----------------
extern "C" void kernel_launch(void* const* d_in, const int* in_sizes, int n_in,
                              void* d_out, int out_size, void* d_ws, size_t ws_size,
                              hipStream_t stream) {
    const float* H = (const float*)d_in[0];
    const int* row[3] = {(const int*)d_in[1], (const int*)d_in[5], (const int*)d_in[9]};
    const int* col[3] = {(const int*)d_in[2], (const int*)d_in[6], (const int*)d_in[10]};
    const float* W[3] = {(const float*)d_in[3], (const float*)d_in[7], (const float*)d_in[11]};
    const float* a[3] = {(const float*)d_in[4], (const float*)d_in[8], (const float*)d_in[12]};
    const float* bias = (const float*)d_in[13];

    const int N = in_sizes[0] / 128;
    const int E = in_sizes[1];
    float* out = (float*)d_out;

    const int L = 3 * N;
    const int nbins = (L + BINW - 1) >> BINSHIFT;   // 147 for N=100k

    char* ws = (char*)d_ws;
    size_t off = 0;
    auto alloc = [&](size_t bytes) -> void* {
        void* p = ws + off;
        off += (bytes + 255) & ~(size_t)255;
        return p;
    };

    ushort* WT = (ushort*)alloc(3 * 16384 * 2);
    ushort* Wh[3];
    for (int r = 0; r < 3; ++r) Wh[r] = (ushort*)alloc((size_t)N * 128 * 2);
    float* sd = (float*)alloc((size_t)L * 4);
    float* ss = (float*)alloc((size_t)L * 4);
    int* offs = (int*)alloc((size_t)L * 4);
    int* bincnt = (int*)alloc((size_t)(nbins + 2) * 4);
    int* binbase = (int*)alloc((size_t)(nbins + 2) * 4);
    int* gbincur = (int*)alloc((size_t)(nbins + 2) * 4);
    uint2* wc = (uint2*)alloc((size_t)3 * E * 8);
    uint2* binned = (uint2*)d_out;  // 24 MB scratch inside the 51.2 MB output buffer

    const int nbG = (N + 127) / 128;
    const int nbQ = (N + 15) / 16;
    const int nbB = (3 * E + 4095) / 4096;

    wt3<<<3, 256, 0, stream>>>(W[0], W[1], W[2], WT);
    gemm3<<<nbG, 256, 0, stream>>>(H, WT, Wh[0], Wh[1], Wh[2], N);
    scores_k<<<nbQ, 256, 0, stream>>>((const uint*)Wh[0], (const uint*)Wh[1], (const uint*)Wh[2],
                                      a[0], a[1], a[2], sd, ss, N);

    hipMemsetAsync(bincnt, 0, (size_t)(nbins + 2) * 4, stream);
    binhist<<<nbB, 256, 0, stream>>>(row[0], row[1], row[2], bincnt, E, N, nbins);
    binscan<<<1, 256, 0, stream>>>(bincnt, binbase, gbincur, nbins, 3 * E);
    binscatter<<<nbB, 256, 0, stream>>>(row[0], row[1], row[2], col[0], col[1], col[2],
                                        sd, ss, gbincur, binned, E, N, nbins);
    binsort<<<nbins, 256, 0, stream>>>(binned, binbase, wc, offs, L);

    aggregate3<<<nbQ, 256, 0, stream>>>((const uint*)Wh[0], (const uint*)Wh[1], (const uint*)Wh[2],
                                        wc, offs, bias, out, N);
}